// Round 13
// baseline (5038.676 us; speedup 1.0000x reference)
//
#include <hip/hip_runtime.h>
#include <hip/hip_bf16.h>

typedef short bf16x8 __attribute__((ext_vector_type(8)));
typedef float f32x4 __attribute__((ext_vector_type(4)));

constexpr int D_  = 768;
constexpr int FF_ = 3072;
constexpr int HH  = 12;      // heads
constexpr int NT_ = 197;     // tokens
constexpr int BB  = 64;      // batch
constexpr int BR  = BB * NT_;   // 12608 real rows
constexpr int MP  = 12800;      // padded rows (100*128 = 200*64)
constexpr int SN  = 224;        // padded sequence
constexpr float SCALE_ = 0.125f; // 64^-0.5

#define MFMA16(a, b, c) __builtin_amdgcn_mfma_f32_16x16x32_bf16((a), (b), (c), 0, 0, 0)

__device__ __forceinline__ void gload_lds16(const __hip_bfloat16* g, __hip_bfloat16* l) {
  __builtin_amdgcn_global_load_lds((const __attribute__((address_space(1))) void*)g,
                                   (__attribute__((address_space(3))) void*)l, 16, 0, 0);
}

// ---------------- small kernels ----------------

__global__ void patch_build(const float* __restrict__ x, __hip_bfloat16* __restrict__ p) {
  int e = blockIdx.x * 256 + threadIdx.x;   // each thread: 4 consecutive pj
  int idx4 = e * 4;
  int col = idx4 % 768; int m = idx4 / 768;
  int c = col >> 8; int pi = (col >> 4) & 15; int pj = col & 15;
  int b = m / 196; int s = m - b * 196; int wi = s / 14; int wj = s - wi * 14;
  const float* src = x + (((size_t)b * 3 + c) * 224 + wi * 16 + pi) * 224 + wj * 16 + pj;
  float4 v = *(const float4*)src;
  __hip_bfloat16* dst = p + (size_t)idx4;
  dst[0] = __float2bfloat16(v.x);
  dst[1] = __float2bfloat16(v.y);
  dst[2] = __float2bfloat16(v.z);
  dst[3] = __float2bfloat16(v.w);
}

__global__ void cls_pos(const float* __restrict__ cls_tok, const float* __restrict__ pos, __hip_bfloat16* __restrict__ t) {
  int e = blockIdx.x * 256 + threadIdx.x;  // 64*768
  int b = e / 768, c = e - (e / 768) * 768;
  t[(size_t)(b * NT_) * D_ + c] = __float2bfloat16(cls_tok[c] + pos[c]);
}

__global__ void cvt_bf16(const float* __restrict__ in, __hip_bfloat16* __restrict__ out) {
  int e = blockIdx.x * 256 + threadIdx.x;
  float4 v = ((const float4*)in)[e];
  union { __hip_bfloat16 h[4]; short4 s4; } u;
  u.h[0] = __float2bfloat16(v.x); u.h[1] = __float2bfloat16(v.y);
  u.h[2] = __float2bfloat16(v.z); u.h[3] = __float2bfloat16(v.w);
  ((short4*)out)[e] = u.s4;
}

// all 4 per-layer weight slabs in one launch (each thread: 4 floats)
__global__ void cvt_layer(const float* __restrict__ qkv, const float* __restrict__ proj,
                          const float* __restrict__ fc1, const float* __restrict__ fc2,
                          __hip_bfloat16* __restrict__ wq, __hip_bfloat16* __restrict__ wp,
                          __hip_bfloat16* __restrict__ w1, __hip_bfloat16* __restrict__ w2) {
  int e = blockIdx.x * 256 + threadIdx.x;
  const float* src; __hip_bfloat16* dst;
  if (e < 442368)       { src = qkv; dst = wq; }
  else if (e < 589824)  { src = proj; dst = wp; e -= 442368; }
  else if (e < 1179648) { src = fc1;  dst = w1; e -= 589824; }
  else                  { src = fc2;  dst = w2; e -= 1179648; }
  float4 v = ((const float4*)src)[e];
  union { __hip_bfloat16 h[4]; short4 s4; } u;
  u.h[0] = __float2bfloat16(v.x); u.h[1] = __float2bfloat16(v.y);
  u.h[2] = __float2bfloat16(v.z); u.h[3] = __float2bfloat16(v.w);
  ((short4*)dst)[e] = u.s4;
}

__global__ void build_bias(const float* __restrict__ rpb, __hip_bfloat16* __restrict__ bias_all) {
  int e = blockIdx.x * 256 + threadIdx.x;   // 12*224*224 threads
  int j = e % SN; int rest = e / SN; int i = rest % SN; int l = rest / SN;
  int idx;
  if (i >= 197 || j >= 197) idx = 0;
  else if (i == 0 && j == 0) idx = 731;
  else if (i == 0) idx = 729;
  else if (j == 0) idx = 730;
  else {
    int pi = i - 1, pj = j - 1;
    int ri = pi / 14, ci = pi - ri * 14, rj = pj / 14, cj = pj - rj * 14;
    idx = (ri - rj + 13) * 27 + (ci - cj + 13);
  }
  const float* src = rpb + ((size_t)l * 732 + idx) * HH;
  __hip_bfloat16* dst = bias_all + ((size_t)l * HH * SN + i) * SN + j;
  #pragma unroll
  for (int h = 0; h < HH; ++h) dst[(size_t)h * SN * SN] = __float2bfloat16(src[h]);
}

__device__ __forceinline__ void block_reduce2(float& s, float& q, int tid) {
  #pragma unroll
  for (int d = 32; d >= 1; d >>= 1) { s += __shfl_xor(s, d); q += __shfl_xor(q, d); }
  __shared__ float ss[4], qq[4];
  int wave = tid >> 6, lane = tid & 63;
  if (lane == 0) { ss[wave] = s; qq[wave] = q; }
  __syncthreads();
  s = ss[0] + ss[1] + ss[2] + ss[3];
  q = qq[0] + qq[1] + qq[2] + qq[3];
}

__global__ __launch_bounds__(256) void ln_rows(const __hip_bfloat16* __restrict__ t, const float* __restrict__ w,
                                               const float* __restrict__ b, __hip_bfloat16* __restrict__ out) {
  int row = blockIdx.x; int tid = threadIdx.x;
  const __hip_bfloat16* x = t + (size_t)row * D_;
  float v0 = __bfloat162float(x[tid]);
  float v1 = __bfloat162float(x[tid + 256]);
  float v2 = __bfloat162float(x[tid + 512]);
  float s = v0 + v1 + v2;
  float q = v0 * v0 + v1 * v1 + v2 * v2;
  block_reduce2(s, q, tid);
  float mu = s * (1.0f / 768.0f);
  float var = q * (1.0f / 768.0f) - mu * mu;
  float rs = rsqrtf(var + 1e-5f);
  __hip_bfloat16* o = out + (size_t)row * D_;
  o[tid]       = __float2bfloat16((v0 - mu) * rs * w[tid]       + b[tid]);
  o[tid + 256] = __float2bfloat16((v1 - mu) * rs * w[tid + 256] + b[tid + 256]);
  o[tid + 512] = __float2bfloat16((v2 - mu) * rs * w[tid + 512] + b[tid + 512]);
}

__global__ __launch_bounds__(256) void pool_ln(const __hip_bfloat16* __restrict__ t, const float* __restrict__ w,
                                               const float* __restrict__ b, float* __restrict__ out) {
  int bimg = blockIdx.x; int tid = threadIdx.x;
  const __hip_bfloat16* base = t + ((size_t)bimg * NT_ + 1) * D_;
  float a0 = 0.f, a1 = 0.f, a2 = 0.f;
  for (int s = 0; s < 196; ++s) {
    const __hip_bfloat16* r = base + (size_t)s * D_;
    a0 += __bfloat162float(r[tid]);
    a1 += __bfloat162float(r[tid + 256]);
    a2 += __bfloat162float(r[tid + 512]);
  }
  a0 *= (1.0f / 196.0f); a1 *= (1.0f / 196.0f); a2 *= (1.0f / 196.0f);
  float s = a0 + a1 + a2;
  float q = a0 * a0 + a1 * a1 + a2 * a2;
  block_reduce2(s, q, tid);
  float mu = s * (1.0f / 768.0f);
  float var = q * (1.0f / 768.0f) - mu * mu;
  float rs = rsqrtf(var + 1e-5f);
  float* o = out + (size_t)bimg * D_;
  o[tid]       = (a0 - mu) * rs * w[tid]       + b[tid];
  o[tid + 256] = (a1 - mu) * rs * w[tid + 256] + b[tid + 256];
  o[tid + 512] = (a2 - mu) * rs * w[tid + 512] + b[tid + 512];
}

// ------- GEMM: C = A @ W^T, serial-staged (round-10 proven loop) -------
// NT_THREADS=512 (8 waves 2Mx4N) for BM=128: LDS 32 KB, LB(512,3) -> 24
// waves/CU (+20% TLP vs round-12's 20). NT_THREADS=256 (4 waves 2Mx2N)
// for BM=64 proj/fc2 (grid 1200 fits one 6-block/CU residency round).
// T2 swizzle (^(row&7)) both sides; T1 bijective XCD swizzle.
// DO NOT force sub-64 VGPR tiers (round-9 spill catastrophe).

enum { EPI_PATCH = 0, EPI_QKV = 1, EPI_GELU = 2, EPI_RESID = 3 };

struct GemmArgs {
  const __hip_bfloat16* A;
  const __hip_bfloat16* W;
  int K;
  int NTILES;
  const float* bias;
  const float* bias2;
  const float* gamma;
  const float* pos;
  __hip_bfloat16* tout;
  __hip_bfloat16* out;
  __hip_bfloat16* qo;
  __hip_bfloat16* ko;
  __hip_bfloat16* vo;
};

template <int MODE, int BM_, int NTHR>
__device__ __forceinline__ void gemm_body(GemmArgs p) {
  static_assert((BM_ == 128 || BM_ == 64) && (NTHR == 256 || NTHR == 512), "");
  constexpr int NWAVE = NTHR / 64;
  constexpr int NWC   = (NWAVE == 8) ? 4 : 2;      // N-waves
  constexpr int NREP  = 4 / (NWC / 2);             // n-frags per wave (2 or 4)
  constexpr int MREP  = BM_ / 32;                  // m-frags per wave
  constexpr int RPI   = NTHR / 8;                  // rows per stage instr (32 or 64)
  const int tid = threadIdx.x, lane = tid & 63, wave = tid >> 6;
  const int wr = wave / NWC, wc = wave % NWC;      // 2M x NWC N
  const int l15 = lane & 15, l4 = lane >> 4;
  const int K = p.K;

  // T1: bijective XCD swizzle (m204)
  const int nwg = gridDim.x;
  const int q = nwg >> 3, rm = nwg & 7;
  const int xcd = blockIdx.x & 7, sub = blockIdx.x >> 3;
  const int swb = (xcd < rm ? xcd * (q + 1) : rm * (q + 1) + (xcd - rm) * q) + sub;
  const int bn = swb % p.NTILES, bm = swb / p.NTILES;

  __shared__ __align__(16) __hip_bfloat16 As[BM_ * 64];
  __shared__ __align__(16) __hip_bfloat16 Bs[128 * 64];

  const int sr = tid >> 3, sc = tid & 7;             // RPI rows x 8 chunks per issue
  const int swz = (sc ^ (sr & 7)) * 8;               // pre-swizzled source chunk
  const __hip_bfloat16* a0 = p.A + (size_t)(bm * BM_ + sr) * K + swz;
  const __hip_bfloat16* b0 = p.W + (size_t)(bn * 128 + sr) * K + swz;
  const int ldsoff = wave * 512;                     // lanes fill +lane*16B (linear)

  auto stage = [&](int t) {
    #pragma unroll
    for (int i = 0; i < BM_ / RPI; ++i)
      gload_lds16(a0 + (size_t)(i * RPI) * K + (size_t)t * 64, &As[i * (RPI * 64) + ldsoff]);
    #pragma unroll
    for (int i = 0; i < 128 / RPI; ++i)
      gload_lds16(b0 + (size_t)(i * RPI) * K + (size_t)t * 64, &Bs[i * (RPI * 64) + ldsoff]);
  };
  auto rdA = [&](int m, int ks) {
    int row = wr * (BM_ / 2) + m * 16 + l15;
    return *(const bf16x8*)&As[row * 64 + (((ks << 2) + l4) ^ (row & 7)) * 8];
  };
  auto rdB = [&](int n, int ks) {
    int row = wc * (16 * NREP) + n * 16 + l15;
    return *(const bf16x8*)&Bs[row * 64 + (((ks << 2) + l4) ^ (row & 7)) * 8];
  };

  f32x4 acc[MREP][NREP] = {};
  const int NKT = K >> 6;
  for (int t = 0; t < NKT; ++t) {
    if (t) asm volatile("s_barrier" ::: "memory");   // all waves done reading LDS
    stage(t);
    asm volatile("s_waitcnt vmcnt(0)" ::: "memory"); // own slice landed
    asm volatile("s_barrier" ::: "memory");          // everyone's slice landed
    #pragma unroll
    for (int ks = 0; ks < 2; ++ks) {
      bf16x8 af[MREP], bfr[NREP];
      #pragma unroll
      for (int m = 0; m < MREP; ++m) af[m] = rdA(m, ks);
      #pragma unroll
      for (int n = 0; n < NREP; ++n) bfr[n] = rdB(n, ks);
      #pragma unroll
      for (int m = 0; m < MREP; ++m)
        #pragma unroll
        for (int n = 0; n < NREP; ++n)
          acc[m][n] = MFMA16(af[m], bfr[n], acc[m][n]);
    }
  }

  const int mb = bm * BM_ + wr * (BM_ / 2);
  const int nbase = bn * 128 + wc * (16 * NREP);
  if constexpr (MODE == EPI_QKV) {
    // j-outer so head/which/hd compute once per output column group
    #pragma unroll
    for (int j = 0; j < NREP; ++j) {
      const int n = nbase + j * 16 + l15;
      const int which = n / D_, d = n - which * D_;
      const int head = d >> 6, hd = d & 63;
      #pragma unroll
      for (int i = 0; i < MREP; ++i) {
        #pragma unroll
        for (int rr = 0; rr < 4; ++rr) {
          const int m = mb + i * 16 + l4 * 4 + rr;
          if (m < BR) {
            const int b = m / NT_, nn = m - (m / NT_) * NT_;
            float v = acc[i][j][rr];
            if (which == 0)
              p.qo[(((size_t)(b * HH + head)) * SN + nn) * 64 + hd] = __float2bfloat16((v + p.bias[d]) * SCALE_);
            else if (which == 1)
              p.ko[(((size_t)(b * HH + head)) * SN + nn) * 64 + hd] = __float2bfloat16(v);
            else
              p.vo[(((size_t)(b * HH + head)) * 64 + hd) * SN + nn] = __float2bfloat16(v + p.bias2[d]);
          }
        }
      }
    }
  } else {
    #pragma unroll
    for (int i = 0; i < MREP; ++i) {
      #pragma unroll
      for (int rr = 0; rr < 4; ++rr) {
        const int m = mb + i * 16 + l4 * 4 + rr;
        if constexpr (MODE == EPI_PATCH) {
          const int b = m / 196, s = m - (m / 196) * 196;
          __hip_bfloat16* dst = p.tout + ((size_t)(b * NT_ + s + 1)) * D_;
          const float* pose = p.pos + (size_t)(s + 1) * D_;
          #pragma unroll
          for (int j = 0; j < NREP; ++j) {
            int n = nbase + j * 16 + l15;
            dst[n] = __float2bfloat16(acc[i][j][rr] + p.bias[n] + pose[n]);
          }
        } else if constexpr (MODE == EPI_GELU) {
          __hip_bfloat16* dst = p.out + (size_t)m * FF_;
          #pragma unroll
          for (int j = 0; j < NREP; ++j) {
            int n = nbase + j * 16 + l15;
            float u = acc[i][j][rr] + p.bias[n];
            float z = 1.59576912f * (u + 0.044715f * u * u * u);
            float g = u * (1.0f / (1.0f + __expf(-z)));   // tanh-form GELU
            dst[n] = __float2bfloat16(g);
          }
        } else {  // EPI_RESID
          if (m < BR) {
            __hip_bfloat16* dst = p.tout + (size_t)m * D_;
            #pragma unroll
            for (int j = 0; j < NREP; ++j) {
              int n = nbase + j * 16 + l15;
              float old = __bfloat162float(dst[n]);
              dst[n] = __float2bfloat16(old + p.gamma[n] * (acc[i][j][rr] + p.bias[n]));
            }
          }
        }
      }
    }
  }
}

// distinct names for rocprof attribution
__global__ __launch_bounds__(512, 3) void gA_patch(GemmArgs p) { gemm_body<EPI_PATCH, 128, 512>(p); }
__global__ __launch_bounds__(512, 3) void gB_qkv(GemmArgs p)   { gemm_body<EPI_QKV, 128, 512>(p); }
__global__ __launch_bounds__(256, 4) void gC_proj(GemmArgs p)  { gemm_body<EPI_RESID, 64, 256>(p); }
__global__ __launch_bounds__(512, 3) void gD_fc1(GemmArgs p)   { gemm_body<EPI_GELU, 128, 512>(p); }
__global__ __launch_bounds__(256, 4) void gE_fc2(GemmArgs p)   { gemm_body<EPI_RESID, 64, 256>(p); }

// ---------------- attention ----------------

__global__ __launch_bounds__(256) void attn_kernel(const __hip_bfloat16* __restrict__ qb,
    const __hip_bfloat16* __restrict__ kb, const __hip_bfloat16* __restrict__ vtb,
    const __hip_bfloat16* __restrict__ biasL, __hip_bfloat16* __restrict__ o) {
  int bh = blockIdx.x; int b = bh / HH, h = bh - b * HH;
  int lane = threadIdx.x & 63, wave = threadIdx.x >> 6;
  int l15 = lane & 15, l4 = lane >> 4;
  __shared__ __align__(16) __hip_bfloat16 probs[4][16][SN];
  const __hip_bfloat16* Q  = qb  + (size_t)bh * SN * 64;
  const __hip_bfloat16* Kp = kb  + (size_t)bh * SN * 64;
  const __hip_bfloat16* VT = vtb + (size_t)bh * 64 * SN;
  const __hip_bfloat16* BIAS = biasL + (size_t)h * SN * SN;
  for (int mt = wave; mt < 13; mt += 4) {
    int m0 = mt * 16;
    bf16x8 qf0 = *(const bf16x8*)(Q + ((size_t)(m0 + l15)) * 64 + l4 * 8);
    bf16x8 qf1 = *(const bf16x8*)(Q + ((size_t)(m0 + l15)) * 64 + 32 + l4 * 8);
    f32x4 sc[14] = {};
    #pragma unroll
    for (int nt = 0; nt < 14; ++nt) {
      bf16x8 kf0 = *(const bf16x8*)(Kp + ((size_t)(nt * 16 + l15)) * 64 + l4 * 8);
      bf16x8 kf1 = *(const bf16x8*)(Kp + ((size_t)(nt * 16 + l15)) * 64 + 32 + l4 * 8);
      sc[nt] = __builtin_amdgcn_mfma_f32_16x16x32_bf16(qf0, kf0, sc[nt], 0, 0, 0);
      sc[nt] = __builtin_amdgcn_mfma_f32_16x16x32_bf16(qf1, kf1, sc[nt], 0, 0, 0);
    }
    float rmax[4] = {-1e30f, -1e30f, -1e30f, -1e30f};
    #pragma unroll
    for (int nt = 0; nt < 14; ++nt) {
      int j = nt * 16 + l15;
      #pragma unroll
      for (int r = 0; r < 4; ++r) {
        int i = m0 + l4 * 4 + r;
        float v = (j < 197) ? (sc[nt][r] + __bfloat162float(BIAS[i * SN + j])) : -1e30f;
        sc[nt][r] = v;
        rmax[r] = fmaxf(rmax[r], v);
      }
    }
    #pragma unroll
    for (int r = 0; r < 4; ++r)
      #pragma unroll
      for (int d = 1; d < 16; d <<= 1)
        rmax[r] = fmaxf(rmax[r], __shfl_xor(rmax[r], d));
    float rsum[4] = {0.f, 0.f, 0.f, 0.f};
    #pragma unroll
    for (int nt = 0; nt < 14; ++nt)
      #pragma unroll
      for (int r = 0; r < 4; ++r) {
        float e = __expf(sc[nt][r] - rmax[r]);
        sc[nt][r] = e;
        rsum[r] += e;
      }
    #pragma unroll
    for (int r = 0; r < 4; ++r) {
      #pragma unroll
      for (int d = 1; d < 16; d <<= 1) rsum[r] += __shfl_xor(rsum[r], d);
      rsum[r] = 1.0f / rsum[r];
    }
    #pragma unroll
    for (int nt = 0; nt < 14; ++nt)
      #pragma unroll
      for (int r = 0; r < 4; ++r)
        probs[wave][l4 * 4 + r][nt * 16 + l15] = __float2bfloat16(sc[nt][r] * rsum[r]);
    asm volatile("s_waitcnt lgkmcnt(0)" ::: "memory");
    __builtin_amdgcn_sched_barrier(0);
    f32x4 oc[4] = {};
    #pragma unroll
    for (int kt = 0; kt < 7; ++kt) {
      bf16x8 pf = *(const bf16x8*)&probs[wave][l15][kt * 32 + l4 * 8];
      #pragma unroll
      for (int nt = 0; nt < 4; ++nt) {
        bf16x8 vf = *(const bf16x8*)(VT + ((size_t)(nt * 16 + l15)) * SN + kt * 32 + l4 * 8);
        oc[nt] = __builtin_amdgcn_mfma_f32_16x16x32_bf16(pf, vf, oc[nt], 0, 0, 0);
      }
    }
    #pragma unroll
    for (int nt = 0; nt < 4; ++nt)
      #pragma unroll
      for (int r = 0; r < 4; ++r) {
        int i = m0 + l4 * 4 + r;
        if (i < 197)
          o[((size_t)(b * NT_ + i)) * D_ + h * 64 + nt * 16 + l15] = __float2bfloat16(oc[nt][r]);
      }
  }
}

// ---------------- host ----------------

extern "C" void kernel_launch(void* const* d_in, const int* in_sizes, int n_in,
                              void* d_out, int out_size, void* d_ws, size_t ws_size,
                              hipStream_t stream) {
  const float* x       = (const float*)d_in[0];
  const float* patch_w = (const float*)d_in[1];
  const float* patch_b = (const float*)d_in[2];
  const float* cls_tok = (const float*)d_in[3];
  const float* pos_emb = (const float*)d_in[4];
  const float* ln1_w   = (const float*)d_in[5];
  const float* ln1_b   = (const float*)d_in[6];
  const float* qkv_w   = (const float*)d_in[7];
  const float* q_bias  = (const float*)d_in[8];
  const float* v_bias  = (const float*)d_in[9];
  const float* proj_w  = (const float*)d_in[10];
  const float* proj_b  = (const float*)d_in[11];
  const float* ln2_w   = (const float*)d_in[12];
  const float* ln2_b   = (const float*)d_in[13];
  const float* fc1_w   = (const float*)d_in[14];
  const float* fc1_b   = (const float*)d_in[15];
  const float* fc2_w   = (const float*)d_in[16];
  const float* fc2_b   = (const float*)d_in[17];
  const float* gamma1  = (const float*)d_in[18];
  const float* gamma2  = (const float*)d_in[19];
  const float* rpb     = (const float*)d_in[20];
  const float* fcn_w   = (const float*)d_in[21];
  const float* fcn_b   = (const float*)d_in[22];
  float* out = (float*)d_out;

  char* ws = (char*)d_ws;
  size_t off = 0;
  auto alloc = [&](size_t bytes) -> void* {
    void* p = ws + off;
    off = (off + bytes + 255) & ~(size_t)255;
    return p;
  };
  __hip_bfloat16* t   = (__hip_bfloat16*)alloc((size_t)MP * D_ * 2);
  __hip_bfloat16* h   = (__hip_bfloat16*)alloc((size_t)MP * D_ * 2);
  __hip_bfloat16* ob  = (__hip_bfloat16*)alloc((size_t)MP * D_ * 2);
  __hip_bfloat16* mid = (__hip_bfloat16*)alloc((size_t)MP * FF_ * 2);   // also patch matrix
  __hip_bfloat16* qb  = (__hip_bfloat16*)alloc((size_t)BB * HH * SN * 64 * 2);
  __hip_bfloat16* kb  = (__hip_bfloat16*)alloc((size_t)BB * HH * SN * 64 * 2);
  __hip_bfloat16* vtb = (__hip_bfloat16*)alloc((size_t)BB * HH * 64 * SN * 2);
  __hip_bfloat16* bias_all = (__hip_bfloat16*)alloc((size_t)12 * HH * SN * SN * 2);
  __hip_bfloat16* wq  = (__hip_bfloat16*)alloc((size_t)2304 * 768 * 2);
  __hip_bfloat16* wp  = (__hip_bfloat16*)alloc((size_t)768 * 768 * 2);
  __hip_bfloat16* w1  = (__hip_bfloat16*)alloc((size_t)3072 * 768 * 2);
  __hip_bfloat16* w2  = (__hip_bfloat16*)alloc((size_t)768 * 3072 * 2);
  __hip_bfloat16* wpt = (__hip_bfloat16*)alloc((size_t)768 * 768 * 2);

  patch_build<<<9408, 256, 0, stream>>>(x, mid);
  cvt_bf16<<<576, 256, 0, stream>>>(patch_w, wpt);
  cls_pos<<<192, 256, 0, stream>>>(cls_tok, pos_emb, t);
  build_bias<<<2352, 256, 0, stream>>>(rpb, bias_all);
  {
    GemmArgs g = {};
    g.A = mid; g.W = wpt; g.K = 768; g.NTILES = 6;
    g.bias = patch_b; g.pos = pos_emb; g.tout = t;
    gA_patch<<<98 * 6, 512, 0, stream>>>(g);   // M = 12544 = 98*128 exact
  }
  for (int l = 0; l < 12; ++l) {
    cvt_layer<<<6912, 256, 0, stream>>>(qkv_w + (size_t)l * 2304 * 768, proj_w + (size_t)l * 768 * 768,
                                        fc1_w + (size_t)l * 3072 * 768, fc2_w + (size_t)l * 768 * 3072,
                                        wq, wp, w1, w2);
    ln_rows<<<BR, 256, 0, stream>>>(t, ln1_w + l * 768, ln1_b + l * 768, h);
    {
      GemmArgs g = {};
      g.A = h; g.W = wq; g.K = 768; g.NTILES = 18;
      g.bias = q_bias + l * 768; g.bias2 = v_bias + l * 768;
      g.qo = qb; g.ko = kb; g.vo = vtb;
      gB_qkv<<<100 * 18, 512, 0, stream>>>(g);
    }
    attn_kernel<<<768, 256, 0, stream>>>(qb, kb, vtb, bias_all + (size_t)l * HH * SN * SN, ob);
    {
      GemmArgs g = {};
      g.A = ob; g.W = wp; g.K = 768; g.NTILES = 6;
      g.bias = proj_b + l * 768; g.gamma = gamma1 + l * 768; g.tout = t;
      gC_proj<<<200 * 6, 256, 0, stream>>>(g);
    }
    ln_rows<<<BR, 256, 0, stream>>>(t, ln2_w + l * 768, ln2_b + l * 768, h);
    {
      GemmArgs g = {};
      g.A = h; g.W = w1; g.K = 768; g.NTILES = 24;
      g.bias = fc1_b + l * 3072; g.out = mid;
      gD_fc1<<<100 * 24, 512, 0, stream>>>(g);
    }
    {
      GemmArgs g = {};
      g.A = mid; g.W = w2; g.K = 3072; g.NTILES = 6;
      g.bias = fc2_b + l * 768; g.gamma = gamma2 + l * 768; g.tout = t;
      gE_fc2<<<200 * 6, 256, 0, stream>>>(g);
    }
  }
  pool_ln<<<64, 256, 0, stream>>>(t, fcn_w, fcn_b, out);
}

// Round 14
// 4848.882 us; speedup vs baseline: 1.0391x; 1.0391x over previous
//
#include <hip/hip_runtime.h>
#include <hip/hip_bf16.h>

typedef short bf16x8 __attribute__((ext_vector_type(8)));
typedef float f32x4 __attribute__((ext_vector_type(4)));

constexpr int D_  = 768;
constexpr int FF_ = 3072;
constexpr int HH  = 12;      // heads
constexpr int NT_ = 197;     // tokens
constexpr int BB  = 64;      // batch
constexpr int BR  = BB * NT_;   // 12608 real rows
constexpr int MP  = 12800;      // padded rows (100*128 = 200*64)
constexpr int SN  = 224;        // padded sequence
constexpr float SCALE_ = 0.125f; // 64^-0.5

#define MFMA16(a, b, c) __builtin_amdgcn_mfma_f32_16x16x32_bf16((a), (b), (c), 0, 0, 0)

__device__ __forceinline__ void gload_lds16(const __hip_bfloat16* g, __hip_bfloat16* l) {
  __builtin_amdgcn_global_load_lds((const __attribute__((address_space(1))) void*)g,
                                   (__attribute__((address_space(3))) void*)l, 16, 0, 0);
}

// ---------------- small kernels ----------------

__global__ void patch_build(const float* __restrict__ x, __hip_bfloat16* __restrict__ p) {
  int e = blockIdx.x * 256 + threadIdx.x;   // each thread: 4 consecutive pj
  int idx4 = e * 4;
  int col = idx4 % 768; int m = idx4 / 768;
  int c = col >> 8; int pi = (col >> 4) & 15; int pj = col & 15;
  int b = m / 196; int s = m - b * 196; int wi = s / 14; int wj = s - wi * 14;
  const float* src = x + (((size_t)b * 3 + c) * 224 + wi * 16 + pi) * 224 + wj * 16 + pj;
  float4 v = *(const float4*)src;
  __hip_bfloat16* dst = p + (size_t)idx4;
  dst[0] = __float2bfloat16(v.x);
  dst[1] = __float2bfloat16(v.y);
  dst[2] = __float2bfloat16(v.z);
  dst[3] = __float2bfloat16(v.w);
}

__global__ void cls_pos(const float* __restrict__ cls_tok, const float* __restrict__ pos, __hip_bfloat16* __restrict__ t) {
  int e = blockIdx.x * 256 + threadIdx.x;  // 64*768
  int b = e / 768, c = e - (e / 768) * 768;
  t[(size_t)(b * NT_) * D_ + c] = __float2bfloat16(cls_tok[c] + pos[c]);
}

__global__ void cvt_bf16(const float* __restrict__ in, __hip_bfloat16* __restrict__ out) {
  int e = blockIdx.x * 256 + threadIdx.x;
  float4 v = ((const float4*)in)[e];
  union { __hip_bfloat16 h[4]; short4 s4; } u;
  u.h[0] = __float2bfloat16(v.x); u.h[1] = __float2bfloat16(v.y);
  u.h[2] = __float2bfloat16(v.z); u.h[3] = __float2bfloat16(v.w);
  ((short4*)out)[e] = u.s4;
}

// all 4 per-layer weight slabs in one launch (each thread: 4 floats)
__global__ void cvt_layer(const float* __restrict__ qkv, const float* __restrict__ proj,
                          const float* __restrict__ fc1, const float* __restrict__ fc2,
                          __hip_bfloat16* __restrict__ wq, __hip_bfloat16* __restrict__ wp,
                          __hip_bfloat16* __restrict__ w1, __hip_bfloat16* __restrict__ w2) {
  int e = blockIdx.x * 256 + threadIdx.x;
  const float* src; __hip_bfloat16* dst;
  if (e < 442368)       { src = qkv; dst = wq; }
  else if (e < 589824)  { src = proj; dst = wp; e -= 442368; }
  else if (e < 1179648) { src = fc1;  dst = w1; e -= 589824; }
  else                  { src = fc2;  dst = w2; e -= 1179648; }
  float4 v = ((const float4*)src)[e];
  union { __hip_bfloat16 h[4]; short4 s4; } u;
  u.h[0] = __float2bfloat16(v.x); u.h[1] = __float2bfloat16(v.y);
  u.h[2] = __float2bfloat16(v.z); u.h[3] = __float2bfloat16(v.w);
  ((short4*)dst)[e] = u.s4;
}

__global__ void build_bias(const float* __restrict__ rpb, __hip_bfloat16* __restrict__ bias_all) {
  int e = blockIdx.x * 256 + threadIdx.x;   // 12*224*224 threads
  int j = e % SN; int rest = e / SN; int i = rest % SN; int l = rest / SN;
  int idx;
  if (i >= 197 || j >= 197) idx = 0;
  else if (i == 0 && j == 0) idx = 731;
  else if (i == 0) idx = 729;
  else if (j == 0) idx = 730;
  else {
    int pi = i - 1, pj = j - 1;
    int ri = pi / 14, ci = pi - ri * 14, rj = pj / 14, cj = pj - rj * 14;
    idx = (ri - rj + 13) * 27 + (ci - cj + 13);
  }
  const float* src = rpb + ((size_t)l * 732 + idx) * HH;
  __hip_bfloat16* dst = bias_all + ((size_t)l * HH * SN + i) * SN + j;
  #pragma unroll
  for (int h = 0; h < HH; ++h) dst[(size_t)h * SN * SN] = __float2bfloat16(src[h]);
}

// V [bh][nn][64] -> VT [bh][64][nn], both sides ushort4-coalesced via LDS tile
__global__ __launch_bounds__(256) void transp_v(const __hip_bfloat16* __restrict__ vb,
                                                __hip_bfloat16* __restrict__ vtb) {
  int bh = blockIdx.x;
  __shared__ unsigned short V_lds[SN][65];
  const unsigned short* src = (const unsigned short*)(vb + (size_t)bh * SN * 64);
  unsigned short* dst = (unsigned short*)(vtb + (size_t)bh * 64 * SN);
  int tid = threadIdx.x;
  #pragma unroll
  for (int c = 0; c < 14; ++c) {
    int id = c * 256 + tid;            // ushort4 index
    int e = id * 4;
    int nn = e >> 6, d = e & 63;
    ushort4 v = ((const ushort4*)src)[id];
    V_lds[nn][d] = v.x; V_lds[nn][d + 1] = v.y; V_lds[nn][d + 2] = v.z; V_lds[nn][d + 3] = v.w;
  }
  __syncthreads();
  #pragma unroll
  for (int c = 0; c < 14; ++c) {
    int id = c * 256 + tid;
    int e = id * 4;
    int d = e / SN, nn = e - d * SN;   // 224 % 4 == 0 so nn..nn+3 stay in row d
    ushort4 v;
    v.x = V_lds[nn][d]; v.y = V_lds[nn + 1][d]; v.z = V_lds[nn + 2][d]; v.w = V_lds[nn + 3][d];
    ((ushort4*)dst)[id] = v;
  }
}

__device__ __forceinline__ void block_reduce2(float& s, float& q, int tid) {
  #pragma unroll
  for (int d = 32; d >= 1; d >>= 1) { s += __shfl_xor(s, d); q += __shfl_xor(q, d); }
  __shared__ float ss[4], qq[4];
  int wave = tid >> 6, lane = tid & 63;
  if (lane == 0) { ss[wave] = s; qq[wave] = q; }
  __syncthreads();
  s = ss[0] + ss[1] + ss[2] + ss[3];
  q = qq[0] + qq[1] + qq[2] + qq[3];
}

__global__ __launch_bounds__(256) void ln_rows(const __hip_bfloat16* __restrict__ t, const float* __restrict__ w,
                                               const float* __restrict__ b, __hip_bfloat16* __restrict__ out) {
  int row = blockIdx.x; int tid = threadIdx.x;
  const __hip_bfloat16* x = t + (size_t)row * D_;
  float v0 = __bfloat162float(x[tid]);
  float v1 = __bfloat162float(x[tid + 256]);
  float v2 = __bfloat162float(x[tid + 512]);
  float s = v0 + v1 + v2;
  float q = v0 * v0 + v1 * v1 + v2 * v2;
  block_reduce2(s, q, tid);
  float mu = s * (1.0f / 768.0f);
  float var = q * (1.0f / 768.0f) - mu * mu;
  float rs = rsqrtf(var + 1e-5f);
  __hip_bfloat16* o = out + (size_t)row * D_;
  o[tid]       = __float2bfloat16((v0 - mu) * rs * w[tid]       + b[tid]);
  o[tid + 256] = __float2bfloat16((v1 - mu) * rs * w[tid + 256] + b[tid + 256]);
  o[tid + 512] = __float2bfloat16((v2 - mu) * rs * w[tid + 512] + b[tid + 512]);
}

__global__ __launch_bounds__(256) void pool_ln(const __hip_bfloat16* __restrict__ t, const float* __restrict__ w,
                                               const float* __restrict__ b, float* __restrict__ out) {
  int bimg = blockIdx.x; int tid = threadIdx.x;
  const __hip_bfloat16* base = t + ((size_t)bimg * NT_ + 1) * D_;
  float a0 = 0.f, a1 = 0.f, a2 = 0.f;
  for (int s = 0; s < 196; ++s) {
    const __hip_bfloat16* r = base + (size_t)s * D_;
    a0 += __bfloat162float(r[tid]);
    a1 += __bfloat162float(r[tid + 256]);
    a2 += __bfloat162float(r[tid + 512]);
  }
  a0 *= (1.0f / 196.0f); a1 *= (1.0f / 196.0f); a2 *= (1.0f / 196.0f);
  float s = a0 + a1 + a2;
  float q = a0 * a0 + a1 * a1 + a2 * a2;
  block_reduce2(s, q, tid);
  float mu = s * (1.0f / 768.0f);
  float var = q * (1.0f / 768.0f) - mu * mu;
  float rs = rsqrtf(var + 1e-5f);
  float* o = out + (size_t)bimg * D_;
  o[tid]       = (a0 - mu) * rs * w[tid]       + b[tid];
  o[tid + 256] = (a1 - mu) * rs * w[tid + 256] + b[tid + 256];
  o[tid + 512] = (a2 - mu) * rs * w[tid + 512] + b[tid + 512];
}

// ------- GEMM: C = A @ W^T, BMx128 tile (BM=128 or 64), BK=64, 256 thr -------
// ROUND-12 PROVEN CONFIG (best: 4886 us). 32/24 KB LDS single-buffered serial
// loop, launch_bounds(256,4); cross-block TLP hides stage/drain (m114).
// T2 swizzle (^(row&7)) both sides; T1 bijective XCD swizzle.
// DO NOT: (256,6) [r9 spill catastrophe], BK=32 [r11 -9%], 512-thr [r13 -3%].

enum { EPI_PATCH = 0, EPI_QKV = 1, EPI_GELU = 2, EPI_RESID = 3 };

struct GemmArgs {
  const __hip_bfloat16* A;
  const __hip_bfloat16* W;
  int K;
  int NTILES;
  const float* bias;
  const float* bias2;
  const float* gamma;
  const float* pos;
  __hip_bfloat16* tout;
  __hip_bfloat16* out;
  __hip_bfloat16* qo;
  __hip_bfloat16* ko;
  __hip_bfloat16* vo;
};

template <int MODE, int BM_>
__device__ __forceinline__ void gemm_body(GemmArgs p) {
  static_assert(BM_ == 128 || BM_ == 64, "");
  constexpr int MREP = BM_ / 32;          // acc m-fragments per wave (4 or 2)
  const int tid = threadIdx.x, lane = tid & 63, wave = tid >> 6;  // 4 waves
  const int wr = wave >> 1, wc = wave & 1;     // 2M x 2N, per-wave (BM_/2)x64
  const int l15 = lane & 15, l4 = lane >> 4;
  const int K = p.K;

  // T1: bijective XCD swizzle (m204)
  const int nwg = gridDim.x;
  const int q = nwg >> 3, rm = nwg & 7;
  const int xcd = blockIdx.x & 7, sub = blockIdx.x >> 3;
  const int swb = (xcd < rm ? xcd * (q + 1) : rm * (q + 1) + (xcd - rm) * q) + sub;
  const int bn = swb % p.NTILES, bm = swb / p.NTILES;

  __shared__ __align__(16) __hip_bfloat16 As[BM_ * 64];
  __shared__ __align__(16) __hip_bfloat16 Bs[128 * 64];

  const int sr = tid >> 3, sc = tid & 7;             // 32 rows x 8 chunks per issue
  const int swz = (sc ^ (sr & 7)) * 8;               // pre-swizzled source chunk
  const __hip_bfloat16* a0 = p.A + (size_t)(bm * BM_ + sr) * K + swz;
  const __hip_bfloat16* b0 = p.W + (size_t)(bn * 128 + sr) * K + swz;
  const int ldsoff = wave * 512;                     // lanes fill +lane*16B (linear)

  auto stage = [&](int t) {                          // BM_/32 + 4 vmem ops
    #pragma unroll
    for (int i = 0; i < BM_ / 32; ++i)
      gload_lds16(a0 + (size_t)(i * 32) * K + (size_t)t * 64, &As[i * 2048 + ldsoff]);
    #pragma unroll
    for (int i = 0; i < 4; ++i)
      gload_lds16(b0 + (size_t)(i * 32) * K + (size_t)t * 64, &Bs[i * 2048 + ldsoff]);
  };
  auto rdA = [&](int m, int ks) {
    int row = wr * (BM_ / 2) + m * 16 + l15;
    return *(const bf16x8*)&As[row * 64 + (((ks << 2) + l4) ^ (row & 7)) * 8];
  };
  auto rdB = [&](int n, int ks) {
    int row = wc * 64 + n * 16 + l15;
    return *(const bf16x8*)&Bs[row * 64 + (((ks << 2) + l4) ^ (row & 7)) * 8];
  };

  f32x4 acc[MREP][4] = {};
  const int NKT = K >> 6;
  for (int t = 0; t < NKT; ++t) {
    if (t) asm volatile("s_barrier" ::: "memory");   // all waves done reading LDS
    stage(t);
    asm volatile("s_waitcnt vmcnt(0)" ::: "memory"); // own slice landed
    asm volatile("s_barrier" ::: "memory");          // everyone's slice landed
    #pragma unroll
    for (int ks = 0; ks < 2; ++ks) {
      bf16x8 af[MREP], bfr[4];
      #pragma unroll
      for (int m = 0; m < MREP; ++m) af[m] = rdA(m, ks);
      #pragma unroll
      for (int n = 0; n < 4; ++n) bfr[n] = rdB(n, ks);
      #pragma unroll
      for (int m = 0; m < MREP; ++m)
        #pragma unroll
        for (int n = 0; n < 4; ++n)
          acc[m][n] = MFMA16(af[m], bfr[n], acc[m][n]);
    }
  }

  const int mb = bm * BM_ + wr * (BM_ / 2);
  const int nbase = bn * 128 + wc * 64;
  if constexpr (MODE == EPI_QKV) {
    // j-outer so head/which/hd compute once per output column group.
    // V written NATURALLY (same addressing as K) -> coalesced; transp_v
    // produces the [bh][64][SN] layout attention consumes.
    #pragma unroll
    for (int j = 0; j < 4; ++j) {
      const int n = nbase + j * 16 + l15;
      const int which = n / D_, d = n - which * D_;
      const int head = d >> 6, hd = d & 63;
      #pragma unroll
      for (int i = 0; i < MREP; ++i) {
        #pragma unroll
        for (int rr = 0; rr < 4; ++rr) {
          const int m = mb + i * 16 + l4 * 4 + rr;
          if (m < BR) {
            const int b = m / NT_, nn = m - (m / NT_) * NT_;
            float v = acc[i][j][rr];
            if (which == 0)
              p.qo[(((size_t)(b * HH + head)) * SN + nn) * 64 + hd] = __float2bfloat16((v + p.bias[d]) * SCALE_);
            else if (which == 1)
              p.ko[(((size_t)(b * HH + head)) * SN + nn) * 64 + hd] = __float2bfloat16(v);
            else
              p.vo[(((size_t)(b * HH + head)) * SN + nn) * 64 + hd] = __float2bfloat16(v + p.bias2[d]);
          }
        }
      }
    }
  } else {
    #pragma unroll
    for (int i = 0; i < MREP; ++i) {
      #pragma unroll
      for (int rr = 0; rr < 4; ++rr) {
        const int m = mb + i * 16 + l4 * 4 + rr;
        if constexpr (MODE == EPI_PATCH) {
          const int b = m / 196, s = m - (m / 196) * 196;
          __hip_bfloat16* dst = p.tout + ((size_t)(b * NT_ + s + 1)) * D_;
          const float* pose = p.pos + (size_t)(s + 1) * D_;
          #pragma unroll
          for (int j = 0; j < 4; ++j) {
            int n = nbase + j * 16 + l15;
            dst[n] = __float2bfloat16(acc[i][j][rr] + p.bias[n] + pose[n]);
          }
        } else if constexpr (MODE == EPI_GELU) {
          __hip_bfloat16* dst = p.out + (size_t)m * FF_;
          #pragma unroll
          for (int j = 0; j < 4; ++j) {
            int n = nbase + j * 16 + l15;
            float u = acc[i][j][rr] + p.bias[n];
            float z = 1.59576912f * (u + 0.044715f * u * u * u);
            float g = u * (1.0f / (1.0f + __expf(-z)));   // tanh-form GELU
            dst[n] = __float2bfloat16(g);
          }
        } else {  // EPI_RESID
          if (m < BR) {
            __hip_bfloat16* dst = p.tout + (size_t)m * D_;
            #pragma unroll
            for (int j = 0; j < 4; ++j) {
              int n = nbase + j * 16 + l15;
              float old = __bfloat162float(dst[n]);
              dst[n] = __float2bfloat16(old + p.gamma[n] * (acc[i][j][rr] + p.bias[n]));
            }
          }
        }
      }
    }
  }
}

// distinct names for rocprof attribution
__global__ __launch_bounds__(256, 4) void gA_patch(GemmArgs p) { gemm_body<EPI_PATCH, 128>(p); }
__global__ __launch_bounds__(256, 4) void gB_qkv(GemmArgs p)   { gemm_body<EPI_QKV, 128>(p); }
__global__ __launch_bounds__(256, 4) void gC_proj(GemmArgs p)  { gemm_body<EPI_RESID, 64>(p); }
__global__ __launch_bounds__(256, 4) void gD_fc1(GemmArgs p)   { gemm_body<EPI_GELU, 128>(p); }
__global__ __launch_bounds__(256, 4) void gE_fc2(GemmArgs p)   { gemm_body<EPI_RESID, 64>(p); }

// ---------------- attention ----------------

__global__ __launch_bounds__(256) void attn_kernel(const __hip_bfloat16* __restrict__ qb,
    const __hip_bfloat16* __restrict__ kb, const __hip_bfloat16* __restrict__ vtb,
    const __hip_bfloat16* __restrict__ biasL, __hip_bfloat16* __restrict__ o) {
  int bh = blockIdx.x; int b = bh / HH, h = bh - b * HH;
  int lane = threadIdx.x & 63, wave = threadIdx.x >> 6;
  int l15 = lane & 15, l4 = lane >> 4;
  __shared__ __align__(16) __hip_bfloat16 probs[4][16][SN];
  const __hip_bfloat16* Q  = qb  + (size_t)bh * SN * 64;
  const __hip_bfloat16* Kp = kb  + (size_t)bh * SN * 64;
  const __hip_bfloat16* VT = vtb + (size_t)bh * 64 * SN;
  const __hip_bfloat16* BIAS = biasL + (size_t)h * SN * SN;
  for (int mt = wave; mt < 13; mt += 4) {
    int m0 = mt * 16;
    bf16x8 qf0 = *(const bf16x8*)(Q + ((size_t)(m0 + l15)) * 64 + l4 * 8);
    bf16x8 qf1 = *(const bf16x8*)(Q + ((size_t)(m0 + l15)) * 64 + 32 + l4 * 8);
    f32x4 sc[14] = {};
    #pragma unroll
    for (int nt = 0; nt < 14; ++nt) {
      bf16x8 kf0 = *(const bf16x8*)(Kp + ((size_t)(nt * 16 + l15)) * 64 + l4 * 8);
      bf16x8 kf1 = *(const bf16x8*)(Kp + ((size_t)(nt * 16 + l15)) * 64 + 32 + l4 * 8);
      sc[nt] = __builtin_amdgcn_mfma_f32_16x16x32_bf16(qf0, kf0, sc[nt], 0, 0, 0);
      sc[nt] = __builtin_amdgcn_mfma_f32_16x16x32_bf16(qf1, kf1, sc[nt], 0, 0, 0);
    }
    float rmax[4] = {-1e30f, -1e30f, -1e30f, -1e30f};
    #pragma unroll
    for (int nt = 0; nt < 14; ++nt) {
      int j = nt * 16 + l15;
      #pragma unroll
      for (int r = 0; r < 4; ++r) {
        int i = m0 + l4 * 4 + r;
        float v = (j < 197) ? (sc[nt][r] + __bfloat162float(BIAS[i * SN + j])) : -1e30f;
        sc[nt][r] = v;
        rmax[r] = fmaxf(rmax[r], v);
      }
    }
    #pragma unroll
    for (int r = 0; r < 4; ++r)
      #pragma unroll
      for (int d = 1; d < 16; d <<= 1)
        rmax[r] = fmaxf(rmax[r], __shfl_xor(rmax[r], d));
    float rsum[4] = {0.f, 0.f, 0.f, 0.f};
    #pragma unroll
    for (int nt = 0; nt < 14; ++nt)
      #pragma unroll
      for (int r = 0; r < 4; ++r) {
        float e = __expf(sc[nt][r] - rmax[r]);
        sc[nt][r] = e;
        rsum[r] += e;
      }
    #pragma unroll
    for (int r = 0; r < 4; ++r) {
      #pragma unroll
      for (int d = 1; d < 16; d <<= 1) rsum[r] += __shfl_xor(rsum[r], d);
      rsum[r] = 1.0f / rsum[r];
    }
    #pragma unroll
    for (int nt = 0; nt < 14; ++nt)
      #pragma unroll
      for (int r = 0; r < 4; ++r)
        probs[wave][l4 * 4 + r][nt * 16 + l15] = __float2bfloat16(sc[nt][r] * rsum[r]);
    asm volatile("s_waitcnt lgkmcnt(0)" ::: "memory");
    __builtin_amdgcn_sched_barrier(0);
    f32x4 oc[4] = {};
    #pragma unroll
    for (int kt = 0; kt < 7; ++kt) {
      bf16x8 pf = *(const bf16x8*)&probs[wave][l15][kt * 32 + l4 * 8];
      #pragma unroll
      for (int nt = 0; nt < 4; ++nt) {
        bf16x8 vf = *(const bf16x8*)(VT + ((size_t)(nt * 16 + l15)) * SN + kt * 32 + l4 * 8);
        oc[nt] = __builtin_amdgcn_mfma_f32_16x16x32_bf16(pf, vf, oc[nt], 0, 0, 0);
      }
    }
    #pragma unroll
    for (int nt = 0; nt < 4; ++nt)
      #pragma unroll
      for (int r = 0; r < 4; ++r) {
        int i = m0 + l4 * 4 + r;
        if (i < 197)
          o[((size_t)(b * NT_ + i)) * D_ + h * 64 + nt * 16 + l15] = __float2bfloat16(oc[nt][r]);
      }
  }
}

// ---------------- host ----------------

extern "C" void kernel_launch(void* const* d_in, const int* in_sizes, int n_in,
                              void* d_out, int out_size, void* d_ws, size_t ws_size,
                              hipStream_t stream) {
  const float* x       = (const float*)d_in[0];
  const float* patch_w = (const float*)d_in[1];
  const float* patch_b = (const float*)d_in[2];
  const float* cls_tok = (const float*)d_in[3];
  const float* pos_emb = (const float*)d_in[4];
  const float* ln1_w   = (const float*)d_in[5];
  const float* ln1_b   = (const float*)d_in[6];
  const float* qkv_w   = (const float*)d_in[7];
  const float* q_bias  = (const float*)d_in[8];
  const float* v_bias  = (const float*)d_in[9];
  const float* proj_w  = (const float*)d_in[10];
  const float* proj_b  = (const float*)d_in[11];
  const float* ln2_w   = (const float*)d_in[12];
  const float* ln2_b   = (const float*)d_in[13];
  const float* fc1_w   = (const float*)d_in[14];
  const float* fc1_b   = (const float*)d_in[15];
  const float* fc2_w   = (const float*)d_in[16];
  const float* fc2_b   = (const float*)d_in[17];
  const float* gamma1  = (const float*)d_in[18];
  const float* gamma2  = (const float*)d_in[19];
  const float* rpb     = (const float*)d_in[20];
  const float* fcn_w   = (const float*)d_in[21];
  const float* fcn_b   = (const float*)d_in[22];
  float* out = (float*)d_out;

  char* ws = (char*)d_ws;
  size_t off = 0;
  auto alloc = [&](size_t bytes) -> void* {
    void* p = ws + off;
    off = (off + bytes + 255) & ~(size_t)255;
    return p;
  };
  __hip_bfloat16* t   = (__hip_bfloat16*)alloc((size_t)MP * D_ * 2);
  __hip_bfloat16* h   = (__hip_bfloat16*)alloc((size_t)MP * D_ * 2);
  __hip_bfloat16* ob  = (__hip_bfloat16*)alloc((size_t)MP * D_ * 2);
  __hip_bfloat16* mid = (__hip_bfloat16*)alloc((size_t)MP * FF_ * 2);   // also patch matrix
  __hip_bfloat16* qb  = (__hip_bfloat16*)alloc((size_t)BB * HH * SN * 64 * 2);
  __hip_bfloat16* kb  = (__hip_bfloat16*)alloc((size_t)BB * HH * SN * 64 * 2);
  __hip_bfloat16* vb  = (__hip_bfloat16*)alloc((size_t)BB * HH * SN * 64 * 2);
  __hip_bfloat16* vtb = (__hip_bfloat16*)alloc((size_t)BB * HH * 64 * SN * 2);
  __hip_bfloat16* bias_all = (__hip_bfloat16*)alloc((size_t)12 * HH * SN * SN * 2);
  __hip_bfloat16* wq  = (__hip_bfloat16*)alloc((size_t)2304 * 768 * 2);
  __hip_bfloat16* wp  = (__hip_bfloat16*)alloc((size_t)768 * 768 * 2);
  __hip_bfloat16* w1  = (__hip_bfloat16*)alloc((size_t)3072 * 768 * 2);
  __hip_bfloat16* w2  = (__hip_bfloat16*)alloc((size_t)768 * 3072 * 2);
  __hip_bfloat16* wpt = (__hip_bfloat16*)alloc((size_t)768 * 768 * 2);

  patch_build<<<9408, 256, 0, stream>>>(x, mid);
  cvt_bf16<<<576, 256, 0, stream>>>(patch_w, wpt);
  cls_pos<<<192, 256, 0, stream>>>(cls_tok, pos_emb, t);
  build_bias<<<2352, 256, 0, stream>>>(rpb, bias_all);
  {
    GemmArgs g = {};
    g.A = mid; g.W = wpt; g.K = 768; g.NTILES = 6;
    g.bias = patch_b; g.pos = pos_emb; g.tout = t;
    gA_patch<<<98 * 6, 256, 0, stream>>>(g);   // M = 12544 = 98*128 exact
  }
  for (int l = 0; l < 12; ++l) {
    cvt_layer<<<6912, 256, 0, stream>>>(qkv_w + (size_t)l * 2304 * 768, proj_w + (size_t)l * 768 * 768,
                                        fc1_w + (size_t)l * 3072 * 768, fc2_w + (size_t)l * 768 * 3072,
                                        wq, wp, w1, w2);
    ln_rows<<<BR, 256, 0, stream>>>(t, ln1_w + l * 768, ln1_b + l * 768, h);
    {
      GemmArgs g = {};
      g.A = h; g.W = wq; g.K = 768; g.NTILES = 18;
      g.bias = q_bias + l * 768; g.bias2 = v_bias + l * 768;
      g.qo = qb; g.ko = kb; g.vo = vb;
      gB_qkv<<<100 * 18, 256, 0, stream>>>(g);
    }
    transp_v<<<768, 256, 0, stream>>>(vb, vtb);
    attn_kernel<<<768, 256, 0, stream>>>(qb, kb, vtb, bias_all + (size_t)l * HH * SN * SN, ob);
    {
      GemmArgs g = {};
      g.A = ob; g.W = wp; g.K = 768; g.NTILES = 6;
      g.bias = proj_b + l * 768; g.gamma = gamma1 + l * 768; g.tout = t;
      gC_proj<<<200 * 6, 256, 0, stream>>>(g);
    }
    ln_rows<<<BR, 256, 0, stream>>>(t, ln2_w + l * 768, ln2_b + l * 768, h);
    {
      GemmArgs g = {};
      g.A = h; g.W = w1; g.K = 768; g.NTILES = 24;
      g.bias = fc1_b + l * 3072; g.out = mid;
      gD_fc1<<<100 * 24, 256, 0, stream>>>(g);
    }
    {
      GemmArgs g = {};
      g.A = mid; g.W = w2; g.K = 3072; g.NTILES = 6;
      g.bias = fc2_b + l * 768; g.gamma = gamma2 + l * 768; g.tout = t;
      gE_fc2<<<200 * 6, 256, 0, stream>>>(g);
    }
  }
  pool_ln<<<64, 256, 0, stream>>>(t, fcn_w, fcn_b, out);
}